// Round 3
// baseline (195.994 us; speedup 1.0000x reference)
//
#include <hip/hip_runtime.h>

// Y = X @ Q where Q is a 512x512 permutation (one-hot) matrix.
// Equivalent to a column gather: Y[n][j] = X[n][map[j]], map[j] = argmax_d Q[d][j].
//
// Memory-bound: 1.074 GB HBM traffic, roofline ~171 us @ 6.29 TB/s measured ceiling.

#define DCOLS 512
#define ROWS_PER_BLOCK 16
#define THREADS 512

// Native vector types (HIP's float4/int4 are classes; the nontemporal
// builtins require true vector types).
typedef float f32x4 __attribute__((ext_vector_type(4)));
typedef int   i32x4 __attribute__((ext_vector_type(4)));

__global__ __launch_bounds__(256)
void build_map_kernel(const float* __restrict__ Q, int* __restrict__ map) {
    int idx = blockIdx.x * 256 + threadIdx.x;   // idx = d*512 + j, covers 512*512
    if (idx < DCOLS * DCOLS) {
        if (Q[idx] > 0.5f) {
            map[idx & (DCOLS - 1)] = idx >> 9;  // map[j] = d
        }
    }
}

__global__ __launch_bounds__(THREADS)
void permute_gather_kernel(const float* __restrict__ X,
                           const int* __restrict__ map,
                           float* __restrict__ out) {
    __shared__ float lds[ROWS_PER_BLOCK * DCOLS];   // 32 KiB -> 4 blocks/CU, 32 waves/CU

    const int t = threadIdx.x;
    const long long n0 = (long long)blockIdx.x * ROWS_PER_BLOCK;

    // Coalesced float4 staging of 16 rows into LDS; nontemporal (touch-once stream).
    const f32x4* src = (const f32x4*)(X + n0 * DCOLS);
    f32x4* l4 = (f32x4*)lds;
    #pragma unroll
    for (int i = 0; i < (ROWS_PER_BLOCK * DCOLS / 4) / THREADS; ++i) {   // 4 iters
        l4[t + i * THREADS] = __builtin_nontemporal_load(&src[t + i * THREADS]);
    }
    __syncthreads();

    // Each thread owns 4 consecutive output columns (one float4) for 4 of the
    // 16 rows. Gather from LDS, write one coalesced nontemporal float4.
    const int jg = t & 127;   // float4 column-group within a row
    const int q  = t >> 7;    // 0..3: which row of each quad
    const i32x4 m = ((const i32x4*)map)[jg];

    #pragma unroll
    for (int rp = 0; rp < ROWS_PER_BLOCK / 4; ++rp) {
        const int row = rp * 4 + q;
        f32x4 o;
        o.x = lds[row * DCOLS + m.x];
        o.y = lds[row * DCOLS + m.y];
        o.z = lds[row * DCOLS + m.z];
        o.w = lds[row * DCOLS + m.w];
        __builtin_nontemporal_store(o, (f32x4*)(out + (n0 + row) * DCOLS) + jg);
    }
}

extern "C" void kernel_launch(void* const* d_in, const int* in_sizes, int n_in,
                              void* d_out, int out_size, void* d_ws, size_t ws_size,
                              hipStream_t stream) {
    const float* X = (const float*)d_in[0];
    const float* Q = (const float*)d_in[1];
    float* out = (float*)d_out;
    int* map = (int*)d_ws;   // 512 ints = 2 KiB scratch

    const int N = in_sizes[0] / DCOLS;   // 262144

    // 1) Build the column->source-row map from Q (deterministic, every call).
    build_map_kernel<<<(DCOLS * DCOLS + 255) / 256, 256, 0, stream>>>(Q, map);

    // 2) Gather.
    permute_gather_kernel<<<N / ROWS_PER_BLOCK, THREADS, 0, stream>>>(X, map, out);
}